// Round 1
// baseline (10521.614 us; speedup 1.0000x reference)
//
#include <hip/hip_runtime.h>

#define B_ 256
#define S_ 128
#define D_ 2
#define H_ 512
#define G4 2048

__device__ __forceinline__ float sigm(float x){ return 1.f/(1.f+__expf(-x)); }
__device__ __forceinline__ float tanh_(float x){ return 1.f - 2.f/(__expf(2.f*x)+1.f); }

// ---------------------------------------------------------------------------
// prep: dxw[j] = dec_bih[j]+dec_bhh[j] - sum_k dec_Wih[j][k]   (x == -1 const)
//       ebias[j] = enc_bih[j]+enc_bhh[j]
// ---------------------------------------------------------------------------
__global__ __launch_bounds__(256) void prep_kernel(
    const float* __restrict__ dWih, const float* __restrict__ dbih,
    const float* __restrict__ dbhh, const float* __restrict__ ebih,
    const float* __restrict__ ebhh, float* __restrict__ dxw,
    float* __restrict__ ebias)
{
    int j = blockIdx.x * 256 + threadIdx.x;   // 0..2047
    const float* row = dWih + (size_t)j * H_;
    float s = 0.f;
    for (int k = 0; k < H_; k++) s += row[k];
    dxw[j]   = dbih[j] + dbhh[j] - s;
    ebias[j] = ebih[j] + ebhh[j];
}

// ---------------------------------------------------------------------------
// Fused LSTM step: z = h @ Whh^T + xpart; gates -> h_out, c_out
// Tile: 32 b x 16 khid x 4 gates; 256 threads; grid (B/32, H/16) = (8,32)
// ---------------------------------------------------------------------------
template<bool ENC>
__global__ __launch_bounds__(256) void lstm_step(
    const float* __restrict__ h_in, int h_stride,
    const float* __restrict__ c_in,
    const float* __restrict__ Whh,    // [2048][512]
    const float* __restrict__ xbias,  // [2048]  (ebias or dxw)
    const float* __restrict__ Wih,    // enc only [2048][2]
    const float* __restrict__ xt,     // enc only: x + t*D_, b-stride S_*D_
    float* __restrict__ h_out, int ho_stride,
    float* __restrict__ c_out)
{
    __shared__ float Hs[32][34];   // [k][b]   (pad 34: even -> b64-aligned)
    __shared__ float Ws[32][68];   // [k][kh*4+g] (pad 68: 272B rows, 16B-aligned)

    const int tid = threadIdx.x;
    const int tx  = tid & 15;      // khid within tile
    const int ty  = tid >> 4;      // b-pair index (handles 2 b)
    const int b0  = blockIdx.x * 32;
    const int kh0 = blockIdx.y * 16;

    float acc[4][2];
#pragma unroll
    for (int g = 0; g < 4; g++) { acc[g][0] = 0.f; acc[g][1] = 0.f; }

    const int lk = tid & 31;   // k within chunk (coalesced dim)
    const int lr = tid >> 5;   // 0..7

    float hreg[4], wreg[8];
    // prefetch chunk 0
#pragma unroll
    for (int i = 0; i < 4; i++) {
        int bl = lr + i * 8;
        hreg[i] = h_in[(size_t)(b0 + bl) * h_stride + lk];
    }
#pragma unroll
    for (int i = 0; i < 8; i++) {
        int p = lr + i * 8; int g = p & 3, kh = p >> 2;
        wreg[i] = Whh[(size_t)(g * H_ + kh0 + kh) * H_ + lk];
    }

    for (int c = 0; c < 16; c++) {
        __syncthreads();
#pragma unroll
        for (int i = 0; i < 4; i++) Hs[lk][lr + i * 8] = hreg[i];
#pragma unroll
        for (int i = 0; i < 8; i++) { int p = lr + i * 8; Ws[lk][p] = wreg[i]; }
        __syncthreads();
        if (c + 1 < 16) {
            int k0 = (c + 1) * 32;
#pragma unroll
            for (int i = 0; i < 4; i++) {
                int bl = lr + i * 8;
                hreg[i] = h_in[(size_t)(b0 + bl) * h_stride + k0 + lk];
            }
#pragma unroll
            for (int i = 0; i < 8; i++) {
                int p = lr + i * 8; int g = p & 3, kh = p >> 2;
                wreg[i] = Whh[(size_t)(g * H_ + kh0 + kh) * H_ + k0 + lk];
            }
        }
#pragma unroll
        for (int k = 0; k < 32; k++) {
            float2 hv = *(const float2*)&Hs[k][2 * ty];
            float4 wv = *(const float4*)&Ws[k][4 * tx];
            acc[0][0] += wv.x * hv.x;  acc[0][1] += wv.x * hv.y;
            acc[1][0] += wv.y * hv.x;  acc[1][1] += wv.y * hv.y;
            acc[2][0] += wv.z * hv.x;  acc[2][1] += wv.z * hv.y;
            acc[3][0] += wv.w * hv.x;  acc[3][1] += wv.w * hv.y;
        }
    }

    const int khid = kh0 + tx;
#pragma unroll
    for (int bb = 0; bb < 2; bb++) {
        int b = b0 + 2 * ty + bb;
        float zi = acc[0][bb] + xbias[0 * H_ + khid];
        float zf = acc[1][bb] + xbias[1 * H_ + khid];
        float zg = acc[2][bb] + xbias[2 * H_ + khid];
        float zo = acc[3][bb] + xbias[3 * H_ + khid];
        if constexpr (ENC) {
            float x0 = xt[b * (S_ * D_) + 0];
            float x1 = xt[b * (S_ * D_) + 1];
            zi += x0 * Wih[(0 * H_ + khid) * D_ + 0] + x1 * Wih[(0 * H_ + khid) * D_ + 1];
            zf += x0 * Wih[(1 * H_ + khid) * D_ + 0] + x1 * Wih[(1 * H_ + khid) * D_ + 1];
            zg += x0 * Wih[(2 * H_ + khid) * D_ + 0] + x1 * Wih[(2 * H_ + khid) * D_ + 1];
            zo += x0 * Wih[(3 * H_ + khid) * D_ + 0] + x1 * Wih[(3 * H_ + khid) * D_ + 1];
        }
        float c_old = c_in[(size_t)b * H_ + khid];
        float ig = sigm(zi), fg = sigm(zf), og = sigm(zo);
        float gg = tanh_(zg);
        float cn = fg * c_old + ig * gg;
        float hn = og * tanh_(cn);
        c_out[(size_t)b * H_ + khid] = cn;
        h_out[(size_t)b * ho_stride + khid] = hn;
    }
}

// ---------------------------------------------------------------------------
// Generic fp32 GEMM:  C[m][n] = sum_k A[m][k]*Bm[n][k] + bias[n]
// ---------------------------------------------------------------------------
template<int BM, int BN, int TM, int TN>
__global__ __launch_bounds__((BM/TM)*(BN/TN)) void gemm_bias(
    const float* __restrict__ A, const float* __restrict__ Bm,
    const float* __restrict__ bias, float* __restrict__ C,
    int M, int N, int K)
{
    constexpr int BK = 32;
    constexpr int TH = (BM / TM) * (BN / TN);
    constexpr int AL = BM * BK / TH;
    constexpr int BL = BN * BK / TH;
    constexpr int RP = TH / BK;
    __shared__ float As[BK][BM + 4];
    __shared__ float Bs[BK][BN + 4];
    const int tid = threadIdx.x;
    const int tn = tid % (BN / TN);
    const int tm = tid / (BN / TN);
    const int m0 = blockIdx.x * BM, n0 = blockIdx.y * BN;
    const int lk = tid % BK, lr = tid / BK;

    float acc[TM][TN];
#pragma unroll
    for (int i = 0; i < TM; i++)
#pragma unroll
        for (int j = 0; j < TN; j++) acc[i][j] = 0.f;

    float areg[AL], breg[BL];
#pragma unroll
    for (int i = 0; i < AL; i++) areg[i] = A[(size_t)(m0 + lr + i * RP) * K + lk];
#pragma unroll
    for (int i = 0; i < BL; i++) breg[i] = Bm[(size_t)(n0 + lr + i * RP) * K + lk];

    const int NC = K / BK;
    for (int c = 0; c < NC; c++) {
        __syncthreads();
#pragma unroll
        for (int i = 0; i < AL; i++) As[lk][lr + i * RP] = areg[i];
#pragma unroll
        for (int i = 0; i < BL; i++) Bs[lk][lr + i * RP] = breg[i];
        __syncthreads();
        if (c + 1 < NC) {
            int k0 = (c + 1) * BK;
#pragma unroll
            for (int i = 0; i < AL; i++) areg[i] = A[(size_t)(m0 + lr + i * RP) * K + k0 + lk];
#pragma unroll
            for (int i = 0; i < BL; i++) breg[i] = Bm[(size_t)(n0 + lr + i * RP) * K + k0 + lk];
        }
#pragma unroll
        for (int k = 0; k < BK; k++) {
            float av[TM], bvv[TN];
#pragma unroll
            for (int i = 0; i < TM; i++) av[i] = As[k][tm * TM + i];
#pragma unroll
            for (int j = 0; j < TN; j++) bvv[j] = Bs[k][tn * TN + j];
#pragma unroll
            for (int i = 0; i < TM; i++)
#pragma unroll
                for (int j = 0; j < TN; j++) acc[i][j] += av[i] * bvv[j];
        }
    }
#pragma unroll
    for (int i = 0; i < TM; i++) {
        int m = m0 + tm * TM + i;
#pragma unroll
        for (int j = 0; j < TN; j++) {
            int n = n0 + tn * TN + j;
            C[(size_t)m * N + n] = acc[i][j] + bias[n];
        }
    }
}

// ---------------------------------------------------------------------------
// Attention step (one block per batch b, 512 threads = 8 waves):
//  u[s]   = sum_k tanh(W1e[b,s,k] + W2h[b,k]) * v[k] + bv
//  a      = softmax(u); out[b][t][s] = a[s]
//  h_glim = sum_s a[s] * enc_hs[b,s,:]
// ---------------------------------------------------------------------------
__global__ __launch_bounds__(512) void attn_step(
    const float* __restrict__ W1e, const float* __restrict__ enc_hs,
    const float* __restrict__ W2h, const float* __restrict__ vv,
    const float* __restrict__ bv, float* __restrict__ out,
    float* __restrict__ h_glim, int t)
{
    __shared__ float q[H_];
    __shared__ float vs[H_];
    __shared__ float u[S_];
    __shared__ float red[8];

    const int b = blockIdx.x;
    const int tid = threadIdx.x;
    const int lane = tid & 63, wave = tid >> 6;

    q[tid]  = W2h[(size_t)b * H_ + tid];
    vs[tid] = vv[tid];
    __syncthreads();

    const float* w1b = W1e + (size_t)b * S_ * H_;
#pragma unroll 2
    for (int si = 0; si < 16; si++) {
        int s = wave * 16 + si;
        const float* row = w1b + (size_t)s * H_ + lane * 8;
        float4 r0 = *(const float4*)(row);
        float4 r1 = *(const float4*)(row + 4);
        float4 q0 = *(const float4*)&q[lane * 8];
        float4 q1 = *(const float4*)&q[lane * 8 + 4];
        float4 v0 = *(const float4*)&vs[lane * 8];
        float4 v1 = *(const float4*)&vs[lane * 8 + 4];
        float sum = tanh_(r0.x + q0.x) * v0.x + tanh_(r0.y + q0.y) * v0.y
                  + tanh_(r0.z + q0.z) * v0.z + tanh_(r0.w + q0.w) * v0.w
                  + tanh_(r1.x + q1.x) * v1.x + tanh_(r1.y + q1.y) * v1.y
                  + tanh_(r1.z + q1.z) * v1.z + tanh_(r1.w + q1.w) * v1.w;
#pragma unroll
        for (int off = 32; off; off >>= 1) sum += __shfl_xor(sum, off);
        if (lane == 0) u[s] = sum + bv[0];
    }
    __syncthreads();

    // softmax over u[0..127] using waves 0,1
    float e = 0.f;
    if (tid < 128) {
        float m = u[tid];
#pragma unroll
        for (int off = 32; off; off >>= 1) m = fmaxf(m, __shfl_xor(m, off));
        if ((tid & 63) == 0) red[tid >> 6] = m;
    }
    __syncthreads();
    float mx = fmaxf(red[0], red[1]);
    if (tid < 128) {
        e = __expf(u[tid] - mx);
        float ss = e;
#pragma unroll
        for (int off = 32; off; off >>= 1) ss += __shfl_xor(ss, off);
        if ((tid & 63) == 0) red[4 + (tid >> 6)] = ss;
    }
    __syncthreads();
    float denom = red[4] + red[5];
    if (tid < 128) {
        float a = e / denom;
        u[tid] = a;
        out[(size_t)b * S_ * S_ + (size_t)t * S_ + tid] = a;
    }
    __syncthreads();

    // glimpse: h_glim[b][tid] = sum_s a[s] * enc_hs[b][s][tid]
    const float* eb = enc_hs + (size_t)b * S_ * H_;
    float acc = 0.f;
#pragma unroll 4
    for (int s = 0; s < S_; s++) acc += u[s] * eb[(size_t)s * H_ + tid];
    h_glim[(size_t)b * H_ + tid] = acc;
}

// ---------------------------------------------------------------------------
extern "C" void kernel_launch(void* const* d_in, const int* in_sizes, int n_in,
                              void* d_out, int out_size, void* d_ws, size_t ws_size,
                              hipStream_t stream)
{
    const float* x    = (const float*)d_in[0];
    const float* eWih = (const float*)d_in[1];
    const float* eWhh = (const float*)d_in[2];
    const float* ebih = (const float*)d_in[3];
    const float* ebhh = (const float*)d_in[4];
    const float* dWih = (const float*)d_in[5];
    const float* dWhh = (const float*)d_in[6];
    const float* dbih = (const float*)d_in[7];
    const float* dbhh = (const float*)d_in[8];
    const float* W1   = (const float*)d_in[9];
    const float* b1   = (const float*)d_in[10];
    const float* W2   = (const float*)d_in[11];
    const float* b2   = (const float*)d_in[12];
    const float* vv   = (const float*)d_in[13];
    const float* bv   = (const float*)d_in[14];
    float* out = (float*)d_out;

    float* ws      = (float*)d_ws;
    float* enc_hs  = ws;                                  // B*S*H
    float* W1e     = enc_hs + (size_t)B_ * S_ * H_;       // B*S*H
    float* h0      = W1e    + (size_t)B_ * S_ * H_;       // B*H (zeros)
    float* c_cur   = h0     + (size_t)B_ * H_;            // B*H
    float* h_dec   = c_cur  + (size_t)B_ * H_;            // B*H
    float* h_glim  = h_dec  + (size_t)B_ * H_;            // B*H
    float* W2h     = h_glim + (size_t)B_ * H_;            // B*H
    float* dxw     = W2h    + (size_t)B_ * H_;            // 2048
    float* ebias   = dxw    + G4;                         // 2048

    hipMemsetAsync(h0, 0, (size_t)B_ * H_ * sizeof(float), stream);
    hipMemsetAsync(c_cur, 0, (size_t)B_ * H_ * sizeof(float), stream);
    prep_kernel<<<8, 256, 0, stream>>>(dWih, dbih, dbhh, ebih, ebhh, dxw, ebias);

    dim3 lgrid(B_ / 32, H_ / 16);   // (8, 32)

    // ---- encoder ----
    for (int t = 0; t < S_; t++) {
        const float* h_in = (t == 0) ? h0 : (enc_hs + (size_t)(t - 1) * H_);
        int h_stride = (t == 0) ? H_ : S_ * H_;
        lstm_step<true><<<lgrid, 256, 0, stream>>>(
            h_in, h_stride, c_cur, eWhh, ebias, eWih, x + t * D_,
            enc_hs + (size_t)t * H_, S_ * H_, c_cur);
    }

    // ---- W1e = enc_hs @ W1^T + b1 ----
    gemm_bias<64, 64, 4, 4><<<dim3((B_ * S_) / 64, H_ / 64), 256, 0, stream>>>(
        enc_hs, W1, b1, W1e, B_ * S_, H_, H_);

    // ---- decoder ----
    for (int t = 0; t < S_; t++) {
        const float* h_in = (t == 0) ? (enc_hs + (size_t)(S_ - 1) * H_) : h_glim;
        int h_stride = (t == 0) ? S_ * H_ : H_;
        lstm_step<false><<<lgrid, 256, 0, stream>>>(
            h_in, h_stride, c_cur, dWhh, dxw, nullptr, nullptr,
            h_dec, H_, c_cur);
        gemm_bias<16, 32, 1, 2><<<dim3(B_ / 16, H_ / 32), 256, 0, stream>>>(
            h_dec, W2, b2, W2h, B_, H_, H_);
        attn_step<<<B_, 512, 0, stream>>>(W1e, enc_hs, W2h, vv, bv, out, h_glim, t);
    }
}